// Round 2
// baseline (597.356 us; speedup 1.0000x reference)
//
#include <hip/hip_runtime.h>
#include <cstdint>
#include <cstddef>

using short8  = __attribute__((ext_vector_type(8))) short;
using floatx4 = __attribute__((ext_vector_type(4))) float;

#define DEV __device__ __forceinline__

DEV float u2f(unsigned short u){
  union { unsigned int i; float f; } c; c.i = ((unsigned int)u) << 16; return c.f;
}
DEV unsigned short f2u(float f){
  union { float f; unsigned int i; } c; c.f = f;
  unsigned int i = c.i;
  i += 0x7fffu + ((i >> 16) & 1u);   // RNE to bf16 (finite values only here)
  return (unsigned short)(i >> 16);
}
DEV float sigmoidf_(float x){ return 1.0f / (1.0f + __expf(-x)); }
DEV float siluf_(float x){ return x / (1.0f + __expf(-x)); }

// async global->LDS, 16 B per lane; LDS dest must be wave-uniform base + lane*16
#define ASYNC_LD16(g, l) __builtin_amdgcn_global_load_lds( \
    (const __attribute__((address_space(1))) unsigned int*)(g), \
    (__attribute__((address_space(3))) unsigned int*)(l), 16, 0, 0)

#define MFMA_BF16 __builtin_amdgcn_mfma_f32_16x16x32_bf16

// problem-fixed sizes: T=2048 S=2048 B=4 E=1024 Z=128
constexpr float SCALING = 0.088388347648318447f; // 128^-0.5

// ---------------------------------------------------------------- casts
__global__ __launch_bounds__(256) void cast_act(
    const float* __restrict__ q, const float* __restrict__ k,
    unsigned short* __restrict__ qo, unsigned short* __restrict__ ko)
{
  const int bid = blockIdx.x;
  const int e = threadIdx.x * 4;
  const float* src; unsigned short* dst;
  if (bid < 8192) {
    src = q + (long long)bid * 1024;
    dst = qo + (long long)bid * 1024;
  } else {
    const int m = bid - 8192;
    const int s = m >> 2, b = m & 3;
    src = k + (long long)m * 1024;
    dst = ko + ((long long)b * 2048 + s) * 1024;
  }
  const float4 v = *(const float4*)(src + e);
  ushort4 o; o.x=f2u(v.x); o.y=f2u(v.y); o.z=f2u(v.z); o.w=f2u(v.w);
  *(ushort4*)(dst + e) = o;
}

__global__ __launch_bounds__(256) void cast_w(
    const float* __restrict__ Wq, const float* __restrict__ Wk,
    const float* __restrict__ Wv, const float* __restrict__ Wh,
    unsigned short* __restrict__ oq, unsigned short* __restrict__ ok,
    unsigned short* __restrict__ ov, unsigned short* __restrict__ oh)
{
  const int bid = blockIdx.x;
  const int e = threadIdx.x * 4;
  const float* src; unsigned short* dst;
  if (bid < 2176)      { src = Wq + (long long)bid * 1024;        dst = oq + (long long)bid * 1024; }
  else if (bid < 2304) { src = Wk + (long long)(bid-2176) * 1024; dst = ok + (long long)(bid-2176) * 1024; }
  else if (bid < 3328) { src = Wv + (long long)(bid-2304) * 1024; dst = ov + (long long)(bid-2304) * 1024; }
  else                 { src = Wh + (long long)(bid-3328) * 1024; dst = oh + (long long)(bid-3328) * 1024; }
  const float4 v = *(const float4*)(src + e);
  ushort4 o; o.x=f2u(v.x); o.y=f2u(v.y); o.z=f2u(v.z); o.w=f2u(v.w);
  *(ushort4*)(dst + e) = o;
}

// ---------------------------------------------------------------- old 128x128 GEMM (proven, R0)
// Kept for N=128 shapes (k-proj and the Wq q-slice). EPI=1 only:
// out = f2u(silu(v + bias[gn]) * gam[gn] + bet[gn]) -> b0[gm*128+gn]
template<int EPI>
__global__ __launch_bounds__(256, 2)
void gemm_bt128(const unsigned short* __restrict__ A, long long bsA, int lda,
                const unsigned short* __restrict__ Bm, long long bsB, int ldb,
                int K,
                const float* __restrict__ bias,
                const float* __restrict__ gam,
                const float* __restrict__ bet,
                unsigned short* __restrict__ b0)
{
  __shared__ __align__(16) unsigned short As[128][64];
  __shared__ __align__(16) unsigned short Bs[128][64];

  const int tid = threadIdx.x;
  const int bm = blockIdx.x, bn = blockIdx.y, bz = blockIdx.z;
  const unsigned short* Ag = A  + (long long)bz * bsA;
  const unsigned short* Bg = Bm + (long long)bz * bsB;
  const int row0 = bm * 128;
  const int col0 = bn * 128;

  const int lane = tid & 63;
  const int wv   = tid >> 6;
  const int wm   = (wv & 1) * 64;
  const int wn   = (wv >> 1) * 64;
  const int lr   = lane & 15;
  const int lq   = lane >> 4;
  const int r7   = lr & 7;

  const unsigned short* gA[4]; const unsigned short* gB[4];
  unsigned short* lA[4]; unsigned short* lB[4];
  #pragma unroll
  for (int i = 0; i < 4; i++) {
    const int c  = tid + i * 256;
    const int rr = c >> 3;
    const int gc = (c & 7) ^ (rr & 7);
    gA[i] = Ag + (long long)(row0 + rr) * lda + gc * 8;
    gB[i] = Bg + (long long)(col0 + rr) * ldb + gc * 8;
    lA[i] = &As[0][0] + c * 8;
    lB[i] = &Bs[0][0] + c * 8;
  }

  floatx4 acc[4][4];
  const floatx4 zero = {0.f, 0.f, 0.f, 0.f};
  #pragma unroll
  for (int i = 0; i < 4; i++)
    #pragma unroll
    for (int j = 0; j < 4; j++) acc[i][j] = zero;

  for (int kt = 0; kt < K; kt += 64) {
    #pragma unroll
    for (int i = 0; i < 4; i++) {
      ASYNC_LD16(gA[i] + kt, lA[i]);
      ASYNC_LD16(gB[i] + kt, lB[i]);
    }
    __syncthreads();
    #pragma unroll
    for (int ks = 0; ks < 64; ks += 32) {
      const int k8 = ks >> 3;
      short8 af[4], bfv[4];
      #pragma unroll
      for (int i = 0; i < 4; i++) {
        const int sc = (lq + k8) ^ r7;
        af[i]  = *(const short8*)(&As[wm + i*16 + lr][sc * 8]);
        bfv[i] = *(const short8*)(&Bs[wn + i*16 + lr][sc * 8]);
      }
      #pragma unroll
      for (int mi = 0; mi < 4; mi++)
        #pragma unroll
        for (int ni = 0; ni < 4; ni++)
          acc[mi][ni] = MFMA_BF16(af[mi], bfv[ni], acc[mi][ni], 0, 0, 0);
    }
    __syncthreads();
  }

  #pragma unroll
  for (int mi = 0; mi < 4; mi++)
    #pragma unroll
    for (int ni = 0; ni < 4; ni++)
      #pragma unroll
      for (int r = 0; r < 4; r++) {
        const int gm = row0 + wm + mi * 16 + lq * 4 + r;
        const int gn = col0 + wn + ni * 16 + lr;
        float v = acc[mi][ni][r] + bias[gn];
        b0[(long long)gm * 128 + gn] = f2u(siluf_(v) * gam[gn] + bet[gn]);
      }
}

// ---------------------------------------------------------------- 256x256 8-phase GEMM (m201 port)
// C[M,N] = A[M,K]*B[N,K]^T. 512 thr = 8 waves (2M x 4N), wave tile 128x64
// (acc 8x4 frags -> FLOP/LDS-byte 42.7 vs 32 at 64x64: LDS off crit path).
// LDS 128 KiB: 2 buffers x (A[256][64] + B[256][64]), XOR-swizzled (0-conflict
// scheme carried from R0). 4 phases/K-tile, each: {ds_read subtile; stage;
// s_barrier; lgkmcnt(0)+sched_barrier(0); setprio(1); 16 MFMA; setprio(0);
// s_barrier}. Counted boundary vmcnt(8): tile t+2 staged during tile t
// (2-ahead stagger, same buffer, into slots freed by ph2/ph3 barriers);
// at tile end, newest 8 outstanding = t+2's -> t+1 guaranteed landed.
// Slot-free proof: B slots read only ph1+ph2 (freed at ph2-end barrier,
// staged ph3); A slots read ph1+ph3 (freed at ph3-end barrier, staged ph4).
// EPI: 0 = Wq main (N=2048 only): u=sigmoid->f0-as-bf16, r=silu->b0
//      2 = v proj swapped: gm=e, gn=(b,s) -> vT coalesced
//      3 = P~=exp(v*SCALING) + atomic rowsum
//      4 = h=acc/rowsum, out=h*r
//      5 = out = q + u*(tanh(.)-q)
template<int EPI>
__global__ __launch_bounds__(512, 2)
void gemm256(const unsigned short* __restrict__ A, long long bsA, int lda,
             const unsigned short* __restrict__ Bm, long long bsB, int ldb,
             int K,
             const float* __restrict__ bias,
             const float* __restrict__ gam,
             const float* __restrict__ bet,
             float* __restrict__ f0,
             unsigned short* __restrict__ b0,
             const unsigned short* __restrict__ rmul,
             const float* __restrict__ qin)
{
  __shared__ __align__(16) unsigned short Ls[65536]; // 128 KiB: [buf2][A 16384 | B 16384]

  const int tid = threadIdx.x;
  const int bm = blockIdx.x, bn = blockIdx.y, bz = blockIdx.z;
  const unsigned short* Ag = A  + (long long)bz * bsA;
  const unsigned short* Bg = Bm + (long long)bz * bsB;
  const int row0 = bm * 256;
  const int col0 = bn * 256;

  const int lane = tid & 63;
  const int wv   = tid >> 6;
  const int wr   = (wv >> 2) * 128;  // wave row offset: 0 / 128
  const int wc   = (wv & 3) * 64;    // wave col offset: 0/64/128/192
  const int lr   = lane & 15;
  const int lq   = lane >> 4;
  const int r7   = lr & 7;

  // staging: instr i covers chunks c = tid + i*512 (rows i*64 .. i*64+63).
  // c&7 and (c>>3)&7 are invariant in i (i*512 -> +64 rows, 64%8==0), so
  // one base + i*(64*ld) suffices.
  const int rr0 = tid >> 3;
  const int swz = ((tid & 7) ^ (rr0 & 7)) * 8;
  const unsigned short* gA0 = Ag + (long long)(row0 + rr0) * lda + swz;
  const unsigned short* gB0 = Bg + (long long)(col0 + rr0) * ldb + swz;
  const long long sA64 = 64LL * lda, sB64 = 64LL * ldb;
  unsigned short* lA0 = &Ls[0]     + tid * 8;   // + i*4096 (+cb for buffer)
  unsigned short* lB0 = &Ls[16384] + tid * 8;

  floatx4 acc[8][4];
  const floatx4 zero = {0.f, 0.f, 0.f, 0.f};
  #pragma unroll
  for (int i = 0; i < 8; i++)
    #pragma unroll
    for (int j = 0; j < 4; j++) acc[i][j] = zero;

  const int NT = K >> 6;  // >= 2 for all shapes here

  // prologue: tile0 -> buf0, tile1 -> buf1; wait tile0 (keep t1's 8 in flight)
  #pragma unroll
  for (int i = 0; i < 4; i++) ASYNC_LD16(gA0 + i * sA64,      lA0 + i * 4096);
  #pragma unroll
  for (int i = 0; i < 4; i++) ASYNC_LD16(gB0 + i * sB64,      lB0 + i * 4096);
  #pragma unroll
  for (int i = 0; i < 4; i++) ASYNC_LD16(gA0 + i * sA64 + 64, lA0 + i * 4096 + 32768);
  #pragma unroll
  for (int i = 0; i < 4; i++) ASYNC_LD16(gB0 + i * sB64 + 64, lB0 + i * 4096 + 32768);
  asm volatile("s_waitcnt vmcnt(8)" ::: "memory");
  __builtin_amdgcn_s_barrier();

  for (int t = 0; t < NT; ++t) {
    const int cb = (t & 1) << 15;   // buffer element offset (32768)
    const unsigned short* Ab = &Ls[cb];
    const unsigned short* Bb = &Ls[cb + 16384];
    const bool st = (t + 2) < NT;
    const int kt2 = (t + 2) << 6;

    short8 afA[4][2], afB[4][2], bf01[2][2], bf23[2][2];

    // ---- phase 1: 12 ds_reads (afA mi0-3, bf01 ni0-1); MFMA Q(0-3, 0-1)
    #pragma unroll
    for (int mi = 0; mi < 4; mi++)
      #pragma unroll
      for (int k = 0; k < 2; k++)
        afA[mi][k] = *(const short8*)(Ab + (wr + mi*16 + lr) * 64 + (((k<<2) + lq) ^ r7) * 8);
    #pragma unroll
    for (int ni = 0; ni < 2; ni++)
      #pragma unroll
      for (int k = 0; k < 2; k++)
        bf01[ni][k] = *(const short8*)(Bb + (wc + ni*16 + lr) * 64 + (((k<<2) + lq) ^ r7) * 8);
    asm volatile("s_waitcnt lgkmcnt(8)" ::: "memory");
    __builtin_amdgcn_s_barrier();
    asm volatile("s_waitcnt lgkmcnt(0)" ::: "memory");
    __builtin_amdgcn_sched_barrier(0);
    __builtin_amdgcn_s_setprio(1);
    #pragma unroll
    for (int mi = 0; mi < 4; mi++)
      #pragma unroll
      for (int ni = 0; ni < 2; ni++)
        #pragma unroll
        for (int k = 0; k < 2; k++)
          acc[mi][ni] = MFMA_BF16(afA[mi][k], bf01[ni][k], acc[mi][ni], 0, 0, 0);
    __builtin_amdgcn_s_setprio(0);
    __builtin_amdgcn_s_barrier();

    // ---- phase 2: 4 ds_reads (bf23 ni2-3); MFMA Q(0-3, 2-3)
    #pragma unroll
    for (int ni = 0; ni < 2; ni++)
      #pragma unroll
      for (int k = 0; k < 2; k++)
        bf23[ni][k] = *(const short8*)(Bb + (wc + (ni+2)*16 + lr) * 64 + (((k<<2) + lq) ^ r7) * 8);
    __builtin_amdgcn_s_barrier();
    asm volatile("s_waitcnt lgkmcnt(0)" ::: "memory");
    __builtin_amdgcn_sched_barrier(0);
    __builtin_amdgcn_s_setprio(1);
    #pragma unroll
    for (int mi = 0; mi < 4; mi++)
      #pragma unroll
      for (int ni = 0; ni < 2; ni++)
        #pragma unroll
        for (int k = 0; k < 2; k++)
          acc[mi][ni+2] = MFMA_BF16(afA[mi][k], bf23[ni][k], acc[mi][ni+2], 0, 0, 0);
    __builtin_amdgcn_s_setprio(0);
    __builtin_amdgcn_s_barrier();   // B slots of this buffer now fully consumed

    // ---- phase 3: 8 ds_reads (afB mi4-7); stage B(t+2) into freed B slots
    #pragma unroll
    for (int mi = 0; mi < 4; mi++)
      #pragma unroll
      for (int k = 0; k < 2; k++)
        afB[mi][k] = *(const short8*)(Ab + (wr + (mi+4)*16 + lr) * 64 + (((k<<2) + lq) ^ r7) * 8);
    if (st) {
      #pragma unroll
      for (int i = 0; i < 4; i++) ASYNC_LD16(gB0 + i * sB64 + kt2, lB0 + i * 4096 + cb);
    }
    __builtin_amdgcn_s_barrier();
    asm volatile("s_waitcnt lgkmcnt(0)" ::: "memory");
    __builtin_amdgcn_sched_barrier(0);
    __builtin_amdgcn_s_setprio(1);
    #pragma unroll
    for (int mi = 0; mi < 4; mi++)
      #pragma unroll
      for (int ni = 0; ni < 2; ni++)
        #pragma unroll
        for (int k = 0; k < 2; k++)
          acc[mi+4][ni] = MFMA_BF16(afB[mi][k], bf01[ni][k], acc[mi+4][ni], 0, 0, 0);
    __builtin_amdgcn_s_setprio(0);
    __builtin_amdgcn_s_barrier();   // A slots of this buffer now fully consumed

    // ---- phase 4: stage A(t+2) into freed A slots; MFMA Q(4-7, 2-3); boundary
    if (st) {
      #pragma unroll
      for (int i = 0; i < 4; i++) ASYNC_LD16(gA0 + i * sA64 + kt2, lA0 + i * 4096 + cb);
    }
    __builtin_amdgcn_s_barrier();
    __builtin_amdgcn_s_setprio(1);
    #pragma unroll
    for (int mi = 0; mi < 4; mi++)
      #pragma unroll
      for (int ni = 0; ni < 2; ni++)
        #pragma unroll
        for (int k = 0; k < 2; k++)
          acc[mi+4][ni+2] = MFMA_BF16(afB[mi][k], bf23[ni][k], acc[mi+4][ni+2], 0, 0, 0);
    __builtin_amdgcn_s_setprio(0);
    // boundary: everything older than t+2's 8 loads (incl. all of t+1) landed
    if (st) { asm volatile("s_waitcnt vmcnt(8)" ::: "memory"); }
    else    { asm volatile("s_waitcnt vmcnt(0)" ::: "memory"); }
    __builtin_amdgcn_s_barrier();
  }

  // ---------------------------------------------------------------- epilogue
  #pragma unroll
  for (int mi = 0; mi < 8; mi++) {
    float s4[4];   // EPI3 partial sums
    float iv[4];   // EPI4 1/rowsum
    if constexpr (EPI == 3) {
      #pragma unroll
      for (int r = 0; r < 4; r++) s4[r] = 0.f;
    }
    if constexpr (EPI == 4) {
      #pragma unroll
      for (int r = 0; r < 4; r++) {
        const int gm = row0 + wr + mi * 16 + lq * 4 + r;
        iv[r] = 1.0f / f0[(long long)bz * 2048 + gm];
      }
    }
    #pragma unroll
    for (int ni = 0; ni < 4; ni++) {
      #pragma unroll
      for (int r = 0; r < 4; r++) {
        const int gm = row0 + wr + mi * 16 + lq * 4 + r;
        const int gn = col0 + wc + ni * 16 + lr;
        float v = acc[mi][ni][r];
        if constexpr (EPI == 0) {
          v += bias[gn];
          if (gn < 1024) {
            ((unsigned short*)f0)[(long long)gm * 1024 + gn] = f2u(sigmoidf_(v)); // u bf16
          } else {
            b0[(long long)gm * 1024 + (gn - 1024)] = f2u(siluf_(v));    // r
          }
        } else if constexpr (EPI == 2) {
          v += bias[gm];                                               // bias by e-row
          const int b = gn >> 11, s = gn & 2047;
          b0[((long long)b * 1024 + gm) * 2048 + s] = f2u(siluf_(v));  // v^T coalesced
        } else if constexpr (EPI == 3) {
          const float e = __expf(v * SCALING);
          b0[(long long)bz * 2048 * 2048 + (long long)gm * 2048 + gn] = f2u(e);
          s4[r] += e;
        } else if constexpr (EPI == 4) {
          const long long idx = ((long long)gm * 4 + bz) * 1024 + gn;  // (t,b,e)
          b0[idx] = f2u(v * iv[r] * u2f(rmul[idx]));                   // h*r
        } else { // EPI == 5
          const long long idx = (long long)gm * 1024 + gn;
          const float tv = tanhf(v + bias[gn]);
          const float qv = qin[idx];
          f0[idx] = qv + u2f(rmul[idx]) * (tv - qv);                   // final out
        }
      }
    }
    if constexpr (EPI == 3) {
      #pragma unroll
      for (int r = 0; r < 4; r++) {
        float s = s4[r];
        #pragma unroll
        for (int m2 = 8; m2 >= 1; m2 >>= 1) s += __shfl_xor(s, m2); // 16-lane group
        if (lr == 0) {
          const int gm = row0 + wr + mi * 16 + lq * 4 + r;
          atomicAdd(f0 + (long long)bz * 2048 + gm, s);
        }
      }
    }
  }
}

// ---------------------------------------------------------------- launch
extern "C" void kernel_launch(void* const* d_in, const int* in_sizes, int n_in,
                              void* d_out, int out_size, void* d_ws, size_t ws_size,
                              hipStream_t stream)
{
  (void)in_sizes; (void)n_in; (void)out_size; (void)ws_size;
  const float* query = (const float*)d_in[0];
  const float* key   = (const float*)d_in[1];
  const float* Wq    = (const float*)d_in[2];
  const float* bq    = (const float*)d_in[3];
  const float* Wk    = (const float*)d_in[4];
  const float* bk    = (const float*)d_in[5];
  const float* Wv    = (const float*)d_in[6];
  const float* bv    = (const float*)d_in[7];
  const float* Wh    = (const float*)d_in[8];
  const float* bh    = (const float*)d_in[9];
  const float* gamma = (const float*)d_in[10];
  const float* beta  = (const float*)d_in[11];
  float* out = (float*)d_out;

  char* p = (char*)d_ws;
  auto take = [&](size_t bytes) -> char* {
    char* r = p; p += (bytes + 255) & ~(size_t)255; return r;
  };
  unsigned short* qbf = (unsigned short*)take(8192ULL * 1024 * 2); // query bf16 (T*B,E)
  unsigned short* kbr = (unsigned short*)take(8192ULL * 1024 * 2); // key bf16 [B][S][E]
  unsigned short* Wqb = (unsigned short*)take(2176ULL * 1024 * 2);
  unsigned short* Wkb = (unsigned short*)take(128ULL  * 1024 * 2);
  unsigned short* Wvb = (unsigned short*)take(1024ULL * 1024 * 2);
  unsigned short* Whb = (unsigned short*)take(1024ULL * 1024 * 2);
  unsigned short* ub  = (unsigned short*)take(8192ULL * 1024 * 2); // u gate bf16
  unsigned short* rbf = (unsigned short*)take(8192ULL * 1024 * 2); // r bf16
  unsigned short* qpj = (unsigned short*)take(8192ULL * 128 * 2);  // q (T,B,Z)
  unsigned short* kpj = (unsigned short*)take(8192ULL * 128 * 2);  // k [B][S][Z]
  unsigned short* vT  = (unsigned short*)take(4ULL * 1024 * 2048 * 2); // v^T [B][E][S]
  unsigned short* Pb  = (unsigned short*)take(4ULL * 2048 * 2048 * 2); // P~ [B][T][S]
  unsigned short* hrb = (unsigned short*)take(8192ULL * 1024 * 2); // h*r bf16
  float*          rs  = (float*)take(4ULL * 2048 * 4);             // rowsums [B][T]

  dim3 blk(256);
  dim3 gblk(512);
  cast_act<<<16384, blk, 0, stream>>>(query, key, qbf, kbr);
  cast_w<<<4352, blk, 0, stream>>>(Wq, Wk, Wv, Wh, Wqb, Wkb, Wvb, Whb);
  hipMemsetAsync(rs, 0, 4ULL * 2048 * 4, stream);

  // q-slice of Wq proj (cols 2048..2175): silu*g0+b0 == EPI1 formula
  gemm_bt128<1><<<dim3(64, 1, 1), blk, 0, stream>>>(qbf, 0, 1024, Wqb + 2048LL*1024, 0, 1024, 1024,
      bq + 2048, gamma, beta, qpj);
  // k[b][s][z] = silu(kbr @ Wk^T + bk)*g1+b1
  gemm_bt128<1><<<dim3(64, 1, 1), blk, 0, stream>>>(kbr, 0, 1024, Wkb, 0, 1024, 1024,
      bk, gamma + 128, beta + 128, kpj);
  // main Wq proj (cols 0..2047): u (sigmoid) + r (silu)
  gemm256<0><<<dim3(32, 8, 1), gblk, 0, stream>>>(qbf, 0, 1024, Wqb, 0, 1024, 1024,
      bq, nullptr, nullptr, (float*)ub, rbf, nullptr, nullptr);
  // v^T[b][e][s] = silu(Wv @ kbr^T + bv)
  gemm256<2><<<dim3(4, 32, 1), gblk, 0, stream>>>(Wvb, 0, 1024, kbr, 0, 1024, 1024,
      bv, nullptr, nullptr, nullptr, vT, nullptr, nullptr);
  // P~[b][t][s] = exp(scaling * q_b @ k_b^T), rowsums -> rs (atomic)
  gemm256<3><<<dim3(8, 8, 4), gblk, 0, stream>>>(qpj, 128, 512, kpj, 2048LL * 128, 128, 128,
      nullptr, nullptr, nullptr, rs, Pb, nullptr, nullptr);
  // hr[t,b,e] = (P~_b @ vT_b^T)/rowsum * r
  gemm256<4><<<dim3(8, 4, 4), gblk, 0, stream>>>(Pb, 2048LL * 2048, 2048,
      vT, 1024LL * 2048, 2048, 2048,
      nullptr, nullptr, nullptr, rs, hrb, rbf, nullptr);
  // out = query + u * (tanh(hr @ Wh^T + bh) - query)
  gemm256<5><<<dim3(32, 4, 1), gblk, 0, stream>>>(hrb, 0, 1024, Whb, 0, 1024, 1024,
      bh, nullptr, nullptr, out, nullptr, ub, query);
}

// Round 3
// 351.759 us; speedup vs baseline: 1.6982x; 1.6982x over previous
//
#include <hip/hip_runtime.h>
#include <cstdint>
#include <cstddef>

using short8  = __attribute__((ext_vector_type(8))) short;
using floatx4 = __attribute__((ext_vector_type(4))) float;

#define DEV __device__ __forceinline__

DEV float u2f(unsigned short u){
  union { unsigned int i; float f; } c; c.i = ((unsigned int)u) << 16; return c.f;
}
DEV unsigned short f2u(float f){
  union { float f; unsigned int i; } c; c.f = f;
  unsigned int i = c.i;
  i += 0x7fffu + ((i >> 16) & 1u);   // RNE to bf16 (finite values only here)
  return (unsigned short)(i >> 16);
}
DEV float sigmoidf_(float x){ return 1.0f / (1.0f + __expf(-x)); }
DEV float siluf_(float x){ return x / (1.0f + __expf(-x)); }

// async global->LDS, 16 B per lane; LDS dest must be wave-uniform base + lane*16
#define ASYNC_LD16(g, l) __builtin_amdgcn_global_load_lds( \
    (const __attribute__((address_space(1))) unsigned int*)(g), \
    (__attribute__((address_space(3))) unsigned int*)(l), 16, 0, 0)

#define MFMA_BF16 __builtin_amdgcn_mfma_f32_16x16x32_bf16

// raw barrier, opaque to the compiler's waitcnt-insertion pass: no implicit
// vmcnt(0) drain can be attached (the R1/R2 catastrophe theory).
#define SBAR() asm volatile("s_barrier" ::: "memory")

// problem-fixed sizes: T=2048 S=2048 B=4 E=1024 Z=128
constexpr float SCALING = 0.088388347648318447f; // 128^-0.5

// ---------------------------------------------------------------- casts
__global__ __launch_bounds__(256) void cast_act(
    const float* __restrict__ q, const float* __restrict__ k,
    unsigned short* __restrict__ qo, unsigned short* __restrict__ ko)
{
  const int bid = blockIdx.x;
  const int e = threadIdx.x * 4;
  const float* src; unsigned short* dst;
  if (bid < 8192) {
    src = q + (long long)bid * 1024;
    dst = qo + (long long)bid * 1024;
  } else {
    const int m = bid - 8192;
    const int s = m >> 2, b = m & 3;
    src = k + (long long)m * 1024;
    dst = ko + ((long long)b * 2048 + s) * 1024;
  }
  const float4 v = *(const float4*)(src + e);
  ushort4 o; o.x=f2u(v.x); o.y=f2u(v.y); o.z=f2u(v.z); o.w=f2u(v.w);
  *(ushort4*)(dst + e) = o;
}

__global__ __launch_bounds__(256) void cast_w(
    const float* __restrict__ Wq, const float* __restrict__ Wk,
    const float* __restrict__ Wv, const float* __restrict__ Wh,
    unsigned short* __restrict__ oq, unsigned short* __restrict__ ok,
    unsigned short* __restrict__ ov, unsigned short* __restrict__ oh)
{
  const int bid = blockIdx.x;
  const int e = threadIdx.x * 4;
  const float* src; unsigned short* dst;
  if (bid < 2176)      { src = Wq + (long long)bid * 1024;        dst = oq + (long long)bid * 1024; }
  else if (bid < 2304) { src = Wk + (long long)(bid-2176) * 1024; dst = ok + (long long)(bid-2176) * 1024; }
  else if (bid < 3328) { src = Wv + (long long)(bid-2304) * 1024; dst = ov + (long long)(bid-2304) * 1024; }
  else                 { src = Wh + (long long)(bid-3328) * 1024; dst = oh + (long long)(bid-3328) * 1024; }
  const float4 v = *(const float4*)(src + e);
  ushort4 o; o.x=f2u(v.x); o.y=f2u(v.y); o.z=f2u(v.z); o.w=f2u(v.w);
  *(ushort4*)(dst + e) = o;
}

// ---------------------------------------------------------------- R0 GEMM (proven)
// C[M,N] = A[M,K] * B[N,K]^T, bf16 in, fp32 acc. 128x128 tile, BK=64,
// single-buffer K-loop, 256 thr = 4 waves (2x2), wave 64x64 via 4x4 MFMA.
// EPI: 2 = v proj SWAPPED (A=Wv, B=kbr): gm=e, gn=(b,s) -> vT coalesced
//      3 = exp epilogue: P~ = exp(v*SCALING) bf16 + atomic fp32 rowsum (f0)
//      4 = PV: h = acc/rowsum, out = h*r (bf16)
//      5 = Wh proj -> out = q + u*(tanh(.)-q)  (fp32; u bf16 via rmul)
template<int EPI>
__global__ __launch_bounds__(256, 2)
void gemm_bt(const unsigned short* __restrict__ A, long long bsA, int lda,
             const unsigned short* __restrict__ Bm, long long bsB, int ldb,
             int K,
             const float* __restrict__ bias,
             const float* __restrict__ gam,
             const float* __restrict__ bet,
             float* __restrict__ f0,
             unsigned short* __restrict__ b0,
             unsigned short* __restrict__ b1,
             const unsigned short* __restrict__ rmul,
             const float* __restrict__ qin)
{
  __shared__ __align__(16) unsigned short As[128][64];
  __shared__ __align__(16) unsigned short Bs[128][64];

  const int tid = threadIdx.x;
  const int bm = blockIdx.x, bn = blockIdx.y, bz = blockIdx.z;
  const unsigned short* Ag = A  + (long long)bz * bsA;
  const unsigned short* Bg = Bm + (long long)bz * bsB;
  const int row0 = bm * 128;
  const int col0 = bn * 128;

  const int lane = tid & 63;
  const int wv   = tid >> 6;
  const int wm   = (wv & 1) * 64;
  const int wn   = (wv >> 1) * 64;
  const int lr   = lane & 15;
  const int lq   = lane >> 4;
  const int r7   = lr & 7;

  const unsigned short* gA[4]; const unsigned short* gB[4];
  unsigned short* lA[4]; unsigned short* lB[4];
  #pragma unroll
  for (int i = 0; i < 4; i++) {
    const int c  = tid + i * 256;
    const int rr = c >> 3;
    const int gc = (c & 7) ^ (rr & 7);
    gA[i] = Ag + (long long)(row0 + rr) * lda + gc * 8;
    gB[i] = Bg + (long long)(col0 + rr) * ldb + gc * 8;
    lA[i] = &As[0][0] + c * 8;
    lB[i] = &Bs[0][0] + c * 8;
  }

  floatx4 acc[4][4];
  const floatx4 zero = {0.f, 0.f, 0.f, 0.f};
  #pragma unroll
  for (int i = 0; i < 4; i++)
    #pragma unroll
    for (int j = 0; j < 4; j++) acc[i][j] = zero;

  for (int kt = 0; kt < K; kt += 64) {
    #pragma unroll
    for (int i = 0; i < 4; i++) {
      ASYNC_LD16(gA[i] + kt, lA[i]);
      ASYNC_LD16(gB[i] + kt, lB[i]);
    }
    __syncthreads();
    #pragma unroll
    for (int ks = 0; ks < 64; ks += 32) {
      const int k8 = ks >> 3;
      short8 af[4], bfv[4];
      #pragma unroll
      for (int i = 0; i < 4; i++) {
        const int sc = (lq + k8) ^ r7;
        af[i]  = *(const short8*)(&As[wm + i*16 + lr][sc * 8]);
        bfv[i] = *(const short8*)(&Bs[wn + i*16 + lr][sc * 8]);
      }
      #pragma unroll
      for (int mi = 0; mi < 4; mi++)
        #pragma unroll
        for (int ni = 0; ni < 4; ni++)
          acc[mi][ni] = MFMA_BF16(af[mi], bfv[ni], acc[mi][ni], 0, 0, 0);
    }
    __syncthreads();
  }

  #pragma unroll
  for (int mi = 0; mi < 4; mi++) {
    float s4[4];
    float iv[4];
    if constexpr (EPI == 3) {
      #pragma unroll
      for (int r = 0; r < 4; r++) s4[r] = 0.f;
    }
    if constexpr (EPI == 4) {
      #pragma unroll
      for (int r = 0; r < 4; r++) {
        const int gm = row0 + wm + mi * 16 + lq * 4 + r;
        iv[r] = 1.0f / f0[(long long)bz * 2048 + gm];
      }
    }
    #pragma unroll
    for (int ni = 0; ni < 4; ni++) {
      #pragma unroll
      for (int r = 0; r < 4; r++) {
        const int gm = row0 + wm + mi * 16 + lq * 4 + r;
        const int gn = col0 + wn + ni * 16 + lr;
        float v = acc[mi][ni][r];
        if constexpr (EPI == 2) {
          v += bias[gm];                                               // bias by e-row
          const int b = gn >> 11, s = gn & 2047;
          b0[((long long)b * 1024 + gm) * 2048 + s] = f2u(siluf_(v));  // v^T coalesced
        } else if constexpr (EPI == 3) {
          const float e = __expf(v * SCALING);
          b0[(long long)bz * 2048 * 2048 + (long long)gm * 2048 + gn] = f2u(e);
          s4[r] += e;
        } else if constexpr (EPI == 4) {
          const long long idx = ((long long)gm * 4 + bz) * 1024 + gn;  // (t,b,e)
          b0[idx] = f2u(v * iv[r] * u2f(rmul[idx]));                   // h*r
        } else { // EPI == 5
          const long long idx = (long long)gm * 1024 + gn;
          const float tv = tanhf(v + bias[gn]);
          const float qv = qin[idx];
          f0[idx] = qv + u2f(rmul[idx]) * (tv - qv);                   // final out
        }
      }
    }
    if constexpr (EPI == 3) {
      #pragma unroll
      for (int r = 0; r < 4; r++) {
        float s = s4[r];
        #pragma unroll
        for (int m2 = 8; m2 >= 1; m2 >>= 1) s += __shfl_xor(s, m2); // 16-lane group
        if (lr == 0) {
          const int gm = row0 + wm + mi * 16 + lq * 4 + r;
          atomicAdd(f0 + (long long)bz * 2048 + gm, s);
        }
      }
    }
  }
}

// ---------------------------------------------------------------- merged N=128 GEMMs
// z=0: qpj = silu(qbf @ WqSlice^T + bq[2048:])*gamma0+beta0   (q projection)
// z=1: kpj = silu(kbr @ Wk^T + bk)*gamma1+beta1                (k projection)
// Same R0 structure; one dispatch of 128 blocks instead of 2x64 (fills GPU).
__global__ __launch_bounds__(256, 2)
void gemm_nz128(const unsigned short* __restrict__ A0, const unsigned short* __restrict__ A1,
                const unsigned short* __restrict__ B0, const unsigned short* __restrict__ B1,
                const float* __restrict__ bi0, const float* __restrict__ bi1,
                const float* __restrict__ g0,  const float* __restrict__ g1,
                const float* __restrict__ be0, const float* __restrict__ be1,
                unsigned short* __restrict__ o0, unsigned short* __restrict__ o1)
{
  __shared__ __align__(16) unsigned short As[128][64];
  __shared__ __align__(16) unsigned short Bs[128][64];

  const int tid = threadIdx.x;
  const int bm = blockIdx.x;
  const int z  = blockIdx.z;
  const unsigned short* Ag = z ? A1 : A0;
  const unsigned short* Bg = z ? B1 : B0;
  const float* bias = z ? bi1 : bi0;
  const float* gam  = z ? g1  : g0;
  const float* bet  = z ? be1 : be0;
  unsigned short* ob = z ? o1 : o0;
  const int row0 = bm * 128;

  const int lane = tid & 63;
  const int wv   = tid >> 6;
  const int wm   = (wv & 1) * 64;
  const int wn   = (wv >> 1) * 64;
  const int lr   = lane & 15;
  const int lq   = lane >> 4;
  const int r7   = lr & 7;

  const unsigned short* gA[4]; const unsigned short* gB[4];
  unsigned short* lA[4]; unsigned short* lB[4];
  #pragma unroll
  for (int i = 0; i < 4; i++) {
    const int c  = tid + i * 256;
    const int rr = c >> 3;
    const int gc = (c & 7) ^ (rr & 7);
    gA[i] = Ag + (long long)(row0 + rr) * 1024 + gc * 8;
    gB[i] = Bg + (long long)rr * 1024 + gc * 8;
    lA[i] = &As[0][0] + c * 8;
    lB[i] = &Bs[0][0] + c * 8;
  }

  floatx4 acc[4][4];
  const floatx4 zero = {0.f, 0.f, 0.f, 0.f};
  #pragma unroll
  for (int i = 0; i < 4; i++)
    #pragma unroll
    for (int j = 0; j < 4; j++) acc[i][j] = zero;

  for (int kt = 0; kt < 1024; kt += 64) {
    #pragma unroll
    for (int i = 0; i < 4; i++) {
      ASYNC_LD16(gA[i] + kt, lA[i]);
      ASYNC_LD16(gB[i] + kt, lB[i]);
    }
    __syncthreads();
    #pragma unroll
    for (int ks = 0; ks < 64; ks += 32) {
      const int k8 = ks >> 3;
      short8 af[4], bfv[4];
      #pragma unroll
      for (int i = 0; i < 4; i++) {
        const int sc = (lq + k8) ^ r7;
        af[i]  = *(const short8*)(&As[wm + i*16 + lr][sc * 8]);
        bfv[i] = *(const short8*)(&Bs[wn + i*16 + lr][sc * 8]);
      }
      #pragma unroll
      for (int mi = 0; mi < 4; mi++)
        #pragma unroll
        for (int ni = 0; ni < 4; ni++)
          acc[mi][ni] = MFMA_BF16(af[mi], bfv[ni], acc[mi][ni], 0, 0, 0);
    }
    __syncthreads();
  }

  #pragma unroll
  for (int mi = 0; mi < 4; mi++)
    #pragma unroll
    for (int ni = 0; ni < 4; ni++)
      #pragma unroll
      for (int r = 0; r < 4; r++) {
        const int gm = row0 + wm + mi * 16 + lq * 4 + r;
        const int gn = wn + ni * 16 + lr;
        float v = acc[mi][ni][r] + bias[gn];
        ob[(long long)gm * 128 + gn] = f2u(siluf_(v) * gam[gn] + bet[gn]);
      }
}

// ---------------------------------------------------------------- 256x256 counted-vmcnt GEMM
// EXPERIMENT (bounded to the Wq-main dispatch): R2 schedule with ALL main-loop
// barriers as raw `asm volatile("s_barrier")` — opaque to SIInsertWaitcnts, so
// the compiler CANNOT attach an implicit vmcnt(0) drain (the R1/R2 stall
// theory: every builtin barrier drained the just-issued prefetch => ~2k cyc
// x 8 barriers/tile = the observed 18k cyc/tile). All correctness waits are
// explicit: lgkmcnt(0)+sched_barrier(0) before MFMA; per-wave counted
// vmcnt(8) at the tile boundary (HK pattern: each wave waits for its own DMA,
// then barrier). EPI0 only: u=sigmoid (f0 as bf16), r=silu (b0). N=2048.
__global__ __launch_bounds__(512, 2)
void gemm256(const unsigned short* __restrict__ A, int lda,
             const unsigned short* __restrict__ Bm, int ldb,
             int K,
             const float* __restrict__ bias,
             float* __restrict__ f0,
             unsigned short* __restrict__ b0)
{
  __shared__ __align__(16) unsigned short Ls[65536]; // 128 KiB: [buf2][A 16384 | B 16384]

  const int tid = threadIdx.x;
  const int bm = blockIdx.x, bn = blockIdx.y;
  const int row0 = bm * 256;
  const int col0 = bn * 256;

  const int lane = tid & 63;
  const int wv   = tid >> 6;
  const int wr   = (wv >> 2) * 128;  // wave row offset: 0 / 128
  const int wc   = (wv & 3) * 64;    // wave col offset: 0/64/128/192
  const int lr   = lane & 15;
  const int lq   = lane >> 4;
  const int r7   = lr & 7;

  const int rr0 = tid >> 3;
  const int swz = ((tid & 7) ^ (rr0 & 7)) * 8;
  const unsigned short* gA0 = A  + (long long)(row0 + rr0) * lda + swz;
  const unsigned short* gB0 = Bm + (long long)(col0 + rr0) * ldb + swz;
  const long long sA64 = 64LL * lda, sB64 = 64LL * ldb;
  unsigned short* lA0 = &Ls[0]     + tid * 8;
  unsigned short* lB0 = &Ls[16384] + tid * 8;

  floatx4 acc[8][4];
  const floatx4 zero = {0.f, 0.f, 0.f, 0.f};
  #pragma unroll
  for (int i = 0; i < 8; i++)
    #pragma unroll
    for (int j = 0; j < 4; j++) acc[i][j] = zero;

  const int NT = K >> 6;

  // prologue: tile0 -> buf0, tile1 -> buf1; wait tile0 only (t1 stays in flight)
  #pragma unroll
  for (int i = 0; i < 4; i++) ASYNC_LD16(gA0 + i * sA64,      lA0 + i * 4096);
  #pragma unroll
  for (int i = 0; i < 4; i++) ASYNC_LD16(gB0 + i * sB64,      lB0 + i * 4096);
  #pragma unroll
  for (int i = 0; i < 4; i++) ASYNC_LD16(gA0 + i * sA64 + 64, lA0 + i * 4096 + 32768);
  #pragma unroll
  for (int i = 0; i < 4; i++) ASYNC_LD16(gB0 + i * sB64 + 64, lB0 + i * 4096 + 32768);
  asm volatile("s_waitcnt vmcnt(8)" ::: "memory");
  SBAR();

  for (int t = 0; t < NT; ++t) {
    const int cb = (t & 1) << 15;
    const unsigned short* Ab = &Ls[cb];
    const unsigned short* Bb = &Ls[cb + 16384];
    const bool st = (t + 2) < NT;
    const int kt2 = (t + 2) << 6;

    short8 afA[4][2], afB[4][2], bf01[2][2], bf23[2][2];

    // ---- phase 1: 12 ds_reads (afA mi0-3, bf01 ni0-1); MFMA Q(0-3, 0-1)
    #pragma unroll
    for (int mi = 0; mi < 4; mi++)
      #pragma unroll
      for (int k = 0; k < 2; k++)
        afA[mi][k] = *(const short8*)(Ab + (wr + mi*16 + lr) * 64 + (((k<<2) + lq) ^ r7) * 8);
    #pragma unroll
    for (int ni = 0; ni < 2; ni++)
      #pragma unroll
      for (int k = 0; k < 2; k++)
        bf01[ni][k] = *(const short8*)(Bb + (wc + ni*16 + lr) * 64 + (((k<<2) + lq) ^ r7) * 8);
    asm volatile("s_waitcnt lgkmcnt(8)" ::: "memory");
    SBAR();
    asm volatile("s_waitcnt lgkmcnt(0)" ::: "memory");
    __builtin_amdgcn_sched_barrier(0);
    __builtin_amdgcn_s_setprio(1);
    #pragma unroll
    for (int mi = 0; mi < 4; mi++)
      #pragma unroll
      for (int ni = 0; ni < 2; ni++)
        #pragma unroll
        for (int k = 0; k < 2; k++)
          acc[mi][ni] = MFMA_BF16(afA[mi][k], bf01[ni][k], acc[mi][ni], 0, 0, 0);
    __builtin_amdgcn_s_setprio(0);
    SBAR();

    // ---- phase 2: 4 ds_reads (bf23 ni2-3); MFMA Q(0-3, 2-3)
    #pragma unroll
    for (int ni = 0; ni < 2; ni++)
      #pragma unroll
      for (int k = 0; k < 2; k++)
        bf23[ni][k] = *(const short8*)(Bb + (wc + (ni+2)*16 + lr) * 64 + (((k<<2) + lq) ^ r7) * 8);
    SBAR();
    asm volatile("s_waitcnt lgkmcnt(0)" ::: "memory");
    __builtin_amdgcn_sched_barrier(0);
    __builtin_amdgcn_s_setprio(1);
    #pragma unroll
    for (int mi = 0; mi < 4; mi++)
      #pragma unroll
      for (int ni = 0; ni < 2; ni++)
        #pragma unroll
        for (int k = 0; k < 2; k++)
          acc[mi][ni+2] = MFMA_BF16(afA[mi][k], bf23[ni][k], acc[mi][ni+2], 0, 0, 0);
    __builtin_amdgcn_s_setprio(0);
    SBAR();   // B slots of this buffer now fully consumed

    // ---- phase 3: 8 ds_reads (afB mi4-7); stage B(t+2) into freed B slots
    #pragma unroll
    for (int mi = 0; mi < 4; mi++)
      #pragma unroll
      for (int k = 0; k < 2; k++)
        afB[mi][k] = *(const short8*)(Ab + (wr + (mi+4)*16 + lr) * 64 + (((k<<2) + lq) ^ r7) * 8);
    if (st) {
      #pragma unroll
      for (int i = 0; i < 4; i++) ASYNC_LD16(gB0 + i * sB64 + kt2, lB0 + i * 4096 + cb);
    }
    SBAR();
    asm volatile("s_waitcnt lgkmcnt(0)" ::: "memory");
    __builtin_amdgcn_sched_barrier(0);
    __builtin_amdgcn_s_setprio(1);
    #pragma unroll
    for (int mi = 0; mi < 4; mi++)
      #pragma unroll
      for (int ni = 0; ni < 2; ni++)
        #pragma unroll
        for (int k = 0; k < 2; k++)
          acc[mi+4][ni] = MFMA_BF16(afB[mi][k], bf01[ni][k], acc[mi+4][ni], 0, 0, 0);
    __builtin_amdgcn_s_setprio(0);
    SBAR();   // A slots of this buffer now fully consumed

    // ---- phase 4: stage A(t+2) into freed A slots; MFMA Q(4-7, 2-3); boundary
    if (st) {
      #pragma unroll
      for (int i = 0; i < 4; i++) ASYNC_LD16(gA0 + i * sA64 + kt2, lA0 + i * 4096 + cb);
    }
    SBAR();
    __builtin_amdgcn_s_setprio(1);
    #pragma unroll
    for (int mi = 0; mi < 4; mi++)
      #pragma unroll
      for (int ni = 0; ni < 2; ni++)
        #pragma unroll
        for (int k = 0; k < 2; k++)
          acc[mi+4][ni+2] = MFMA_BF16(afB[mi][k], bf23[ni][k], acc[mi+4][ni+2], 0, 0, 0);
    __builtin_amdgcn_s_setprio(0);
    // boundary: wait everything older than t+2's 8 loads => t+1 fully landed
    if (st) { asm volatile("s_waitcnt vmcnt(8)" ::: "memory"); }
    else    { asm volatile("s_waitcnt vmcnt(0)" ::: "memory"); }
    SBAR();
  }

  // epilogue (EPI0, N=2048: u for gn<1024 else r)
  #pragma unroll
  for (int mi = 0; mi < 8; mi++)
    #pragma unroll
    for (int ni = 0; ni < 4; ni++)
      #pragma unroll
      for (int r = 0; r < 4; r++) {
        const int gm = row0 + wr + mi * 16 + lq * 4 + r;
        const int gn = col0 + wc + ni * 16 + lr;
        float v = acc[mi][ni][r] + bias[gn];
        if (gn < 1024) {
          ((unsigned short*)f0)[(long long)gm * 1024 + gn] = f2u(sigmoidf_(v)); // u bf16
        } else {
          b0[(long long)gm * 1024 + (gn - 1024)] = f2u(siluf_(v));    // r
        }
      }
}

// ---------------------------------------------------------------- launch
extern "C" void kernel_launch(void* const* d_in, const int* in_sizes, int n_in,
                              void* d_out, int out_size, void* d_ws, size_t ws_size,
                              hipStream_t stream)
{
  (void)in_sizes; (void)n_in; (void)out_size; (void)ws_size;
  const float* query = (const float*)d_in[0];
  const float* key   = (const float*)d_in[1];
  const float* Wq    = (const float*)d_in[2];
  const float* bq    = (const float*)d_in[3];
  const float* Wk    = (const float*)d_in[4];
  const float* bk    = (const float*)d_in[5];
  const float* Wv    = (const float*)d_in[6];
  const float* bv    = (const float*)d_in[7];
  const float* Wh    = (const float*)d_in[8];
  const float* bh    = (const float*)d_in[9];
  const float* gamma = (const float*)d_in[10];
  const float* beta  = (const float*)d_in[11];
  float* out = (float*)d_out;

  char* p = (char*)d_ws;
  auto take = [&](size_t bytes) -> char* {
    char* r = p; p += (bytes + 255) & ~(size_t)255; return r;
  };
  unsigned short* qbf = (unsigned short*)take(8192ULL * 1024 * 2); // query bf16 (T*B,E)
  unsigned short* kbr = (unsigned short*)take(8192ULL * 1024 * 2); // key bf16 [B][S][E]
  unsigned short* Wqb = (unsigned short*)take(2176ULL * 1024 * 2);
  unsigned short* Wkb = (unsigned short*)take(128ULL  * 1024 * 2);
  unsigned short* Wvb = (unsigned short*)take(1024ULL * 1024 * 2);
  unsigned short* Whb = (unsigned short*)take(1024ULL * 1024 * 2);
  unsigned short* ub  = (unsigned short*)take(8192ULL * 1024 * 2); // u gate bf16
  unsigned short* rbf = (unsigned short*)take(8192ULL * 1024 * 2); // r bf16
  unsigned short* qpj = (unsigned short*)take(8192ULL * 128 * 2);  // q (T,B,Z)
  unsigned short* kpj = (unsigned short*)take(8192ULL * 128 * 2);  // k [B][S][Z]
  unsigned short* vT  = (unsigned short*)take(4ULL * 1024 * 2048 * 2); // v^T [B][E][S]
  unsigned short* Pb  = (unsigned short*)take(4ULL * 2048 * 2048 * 2); // P~ [B][T][S]
  unsigned short* hrb = (unsigned short*)take(8192ULL * 1024 * 2); // h*r bf16
  float*          rs  = (float*)take(4ULL * 2048 * 4);             // rowsums [B][T]

  dim3 blk(256);
  dim3 gblk(512);
  cast_act<<<16384, blk, 0, stream>>>(query, key, qbf, kbr);
  cast_w<<<4352, blk, 0, stream>>>(Wq, Wk, Wv, Wh, Wqb, Wkb, Wvb, Whb);
  hipMemsetAsync(rs, 0, 4ULL * 2048 * 4, stream);

  // merged N=128 projections: z=0 q-slice (Wq rows 2048..2175), z=1 k-proj
  gemm_nz128<<<dim3(64, 1, 2), blk, 0, stream>>>(
      qbf, kbr, Wqb + 2048LL * 1024, Wkb,
      bq + 2048, bk, gamma, gamma + 128, beta, beta + 128, qpj, kpj);
  // EXPERIMENT: Wq main (cols 0..2047) on counted-vmcnt 256x256 kernel
  gemm256<<<dim3(32, 8, 1), gblk, 0, stream>>>(qbf, 1024, Wqb, 1024, 1024,
      bq, (float*)ub, rbf);
  // v^T[b][e][s] = silu(Wv @ kbr^T + bv)   (R0 structure)
  gemm_bt<2><<<dim3(8, 64, 1), blk, 0, stream>>>(Wvb, 0, 1024, kbr, 0, 1024, 1024,
      bv, nullptr, nullptr, nullptr, vT, nullptr, nullptr, nullptr);
  // P~[b][t][s] = exp(scaling * q_b @ k_b^T), rowsums -> rs (atomic)
  gemm_bt<3><<<dim3(16, 16, 4), blk, 0, stream>>>(qpj, 128, 512, kpj, 2048LL * 128, 128, 128,
      nullptr, nullptr, nullptr, rs, Pb, nullptr, nullptr, nullptr);
  // hr[t,b,e] = (P~_b @ vT_b^T)/rowsum * r
  gemm_bt<4><<<dim3(16, 8, 4), blk, 0, stream>>>(Pb, 2048LL * 2048, 2048,
      vT, 1024LL * 2048, 2048, 2048,
      nullptr, nullptr, nullptr, rs, hrb, nullptr, rbf, nullptr);
  // out = query + u * (tanh(hr @ Wh^T + bh) - query)
  gemm_bt<5><<<dim3(64, 8, 1), blk, 0, stream>>>(hrb, 0, 1024, Whb, 0, 1024, 1024,
      bh, nullptr, nullptr, out, nullptr, nullptr, ub, query);
}

// Round 4
// 342.220 us; speedup vs baseline: 1.7455x; 1.0279x over previous
//
#include <hip/hip_runtime.h>
#include <cstdint>
#include <cstddef>

using short8  = __attribute__((ext_vector_type(8))) short;
using floatx4 = __attribute__((ext_vector_type(4))) float;

#define DEV __device__ __forceinline__

DEV float u2f(unsigned short u){
  union { unsigned int i; float f; } c; c.i = ((unsigned int)u) << 16; return c.f;
}
DEV unsigned short f2u(float f){
  union { float f; unsigned int i; } c; c.f = f;
  unsigned int i = c.i;
  i += 0x7fffu + ((i >> 16) & 1u);   // RNE to bf16 (finite values only here)
  return (unsigned short)(i >> 16);
}
DEV float sigmoidf_(float x){ return 1.0f / (1.0f + __expf(-x)); }
DEV float siluf_(float x){ return x / (1.0f + __expf(-x)); }

// async global->LDS, 16 B per lane; LDS dest must be wave-uniform base + lane*16
#define ASYNC_LD16(g, l) __builtin_amdgcn_global_load_lds( \
    (const __attribute__((address_space(1))) unsigned int*)(g), \
    (__attribute__((address_space(3))) unsigned int*)(l), 16, 0, 0)

#define MFMA_BF16 __builtin_amdgcn_mfma_f32_16x16x32_bf16

// raw barrier, opaque to the compiler's waitcnt-insertion pass: no implicit
// vmcnt(0) drain can be attached (R3-proven: 122us -> 53.8us on gemm256).
#define SBAR() asm volatile("s_barrier" ::: "memory")

// problem-fixed sizes: T=2048 S=2048 B=4 E=1024 Z=128
constexpr float SCALING = 0.088388347648318447f; // 128^-0.5

// ---------------------------------------------------------------- casts
__global__ __launch_bounds__(256) void cast_act(
    const float* __restrict__ q, const float* __restrict__ k,
    unsigned short* __restrict__ qo, unsigned short* __restrict__ ko)
{
  const int bid = blockIdx.x;
  const int e = threadIdx.x * 4;
  const float* src; unsigned short* dst;
  if (bid < 8192) {
    src = q + (long long)bid * 1024;
    dst = qo + (long long)bid * 1024;
  } else {
    const int m = bid - 8192;
    const int s = m >> 2, b = m & 3;
    src = k + (long long)m * 1024;
    dst = ko + ((long long)b * 2048 + s) * 1024;
  }
  const float4 v = *(const float4*)(src + e);
  ushort4 o; o.x=f2u(v.x); o.y=f2u(v.y); o.z=f2u(v.z); o.w=f2u(v.w);
  *(ushort4*)(dst + e) = o;
}

__global__ __launch_bounds__(256) void cast_w(
    const float* __restrict__ Wq, const float* __restrict__ Wk,
    const float* __restrict__ Wv, const float* __restrict__ Wh,
    unsigned short* __restrict__ oq, unsigned short* __restrict__ ok,
    unsigned short* __restrict__ ov, unsigned short* __restrict__ oh)
{
  const int bid = blockIdx.x;
  const int e = threadIdx.x * 4;
  const float* src; unsigned short* dst;
  if (bid < 2176)      { src = Wq + (long long)bid * 1024;        dst = oq + (long long)bid * 1024; }
  else if (bid < 2304) { src = Wk + (long long)(bid-2176) * 1024; dst = ok + (long long)(bid-2176) * 1024; }
  else if (bid < 3328) { src = Wv + (long long)(bid-2304) * 1024; dst = ov + (long long)(bid-2304) * 1024; }
  else                 { src = Wh + (long long)(bid-3328) * 1024; dst = oh + (long long)(bid-3328) * 1024; }
  const float4 v = *(const float4*)(src + e);
  ushort4 o; o.x=f2u(v.x); o.y=f2u(v.y); o.z=f2u(v.z); o.w=f2u(v.w);
  *(ushort4*)(dst + e) = o;
}

// ---------------------------------------------------------------- R0 GEMM (proven)
// Kept for g3 only (K=128: pipeline degenerates, epilogue has atomics).
// EPI 3 = exp epilogue: P~ = exp(v*SCALING) bf16 + atomic fp32 rowsum (f0)
template<int EPI>
__global__ __launch_bounds__(256, 2)
void gemm_bt(const unsigned short* __restrict__ A, long long bsA, int lda,
             const unsigned short* __restrict__ Bm, long long bsB, int ldb,
             int K,
             float* __restrict__ f0,
             unsigned short* __restrict__ b0)
{
  __shared__ __align__(16) unsigned short As[128][64];
  __shared__ __align__(16) unsigned short Bs[128][64];

  const int tid = threadIdx.x;
  const int bm = blockIdx.x, bn = blockIdx.y, bz = blockIdx.z;
  const unsigned short* Ag = A  + (long long)bz * bsA;
  const unsigned short* Bg = Bm + (long long)bz * bsB;
  const int row0 = bm * 128;
  const int col0 = bn * 128;

  const int lane = tid & 63;
  const int wv   = tid >> 6;
  const int wm   = (wv & 1) * 64;
  const int wn   = (wv >> 1) * 64;
  const int lr   = lane & 15;
  const int lq   = lane >> 4;
  const int r7   = lr & 7;

  const unsigned short* gA[4]; const unsigned short* gB[4];
  unsigned short* lA[4]; unsigned short* lB[4];
  #pragma unroll
  for (int i = 0; i < 4; i++) {
    const int c  = tid + i * 256;
    const int rr = c >> 3;
    const int gc = (c & 7) ^ (rr & 7);
    gA[i] = Ag + (long long)(row0 + rr) * lda + gc * 8;
    gB[i] = Bg + (long long)(col0 + rr) * ldb + gc * 8;
    lA[i] = &As[0][0] + c * 8;
    lB[i] = &Bs[0][0] + c * 8;
  }

  floatx4 acc[4][4];
  const floatx4 zero = {0.f, 0.f, 0.f, 0.f};
  #pragma unroll
  for (int i = 0; i < 4; i++)
    #pragma unroll
    for (int j = 0; j < 4; j++) acc[i][j] = zero;

  for (int kt = 0; kt < K; kt += 64) {
    #pragma unroll
    for (int i = 0; i < 4; i++) {
      ASYNC_LD16(gA[i] + kt, lA[i]);
      ASYNC_LD16(gB[i] + kt, lB[i]);
    }
    __syncthreads();
    #pragma unroll
    for (int ks = 0; ks < 64; ks += 32) {
      const int k8 = ks >> 3;
      short8 af[4], bfv[4];
      #pragma unroll
      for (int i = 0; i < 4; i++) {
        const int sc = (lq + k8) ^ r7;
        af[i]  = *(const short8*)(&As[wm + i*16 + lr][sc * 8]);
        bfv[i] = *(const short8*)(&Bs[wn + i*16 + lr][sc * 8]);
      }
      #pragma unroll
      for (int mi = 0; mi < 4; mi++)
        #pragma unroll
        for (int ni = 0; ni < 4; ni++)
          acc[mi][ni] = MFMA_BF16(af[mi], bfv[ni], acc[mi][ni], 0, 0, 0);
    }
    __syncthreads();
  }

  #pragma unroll
  for (int mi = 0; mi < 4; mi++) {
    float s4[4];
    #pragma unroll
    for (int r = 0; r < 4; r++) s4[r] = 0.f;
    #pragma unroll
    for (int ni = 0; ni < 4; ni++) {
      #pragma unroll
      for (int r = 0; r < 4; r++) {
        const int gm = row0 + wm + mi * 16 + lq * 4 + r;
        const int gn = col0 + wn + ni * 16 + lr;
        const float e = __expf(acc[mi][ni][r] * SCALING);
        b0[(long long)bz * 2048 * 2048 + (long long)gm * 2048 + gn] = f2u(e);
        s4[r] += e;
      }
    }
    #pragma unroll
    for (int r = 0; r < 4; r++) {
      float s = s4[r];
      #pragma unroll
      for (int m2 = 8; m2 >= 1; m2 >>= 1) s += __shfl_xor(s, m2); // 16-lane group
      if (lr == 0) {
        const int gm = row0 + wm + mi * 16 + lq * 4 + r;
        atomicAdd(f0 + (long long)bz * 2048 + gm, s);
      }
    }
  }
}

// ---------------------------------------------------------------- merged N=128 GEMMs
// z=0: qpj = silu(qbf @ WqSlice^T + bq[2048:])*gamma0+beta0   (q projection)
// z=1: kpj = silu(kbr @ Wk^T + bk)*gamma1+beta1                (k projection)
__global__ __launch_bounds__(256, 2)
void gemm_nz128(const unsigned short* __restrict__ A0, const unsigned short* __restrict__ A1,
                const unsigned short* __restrict__ B0, const unsigned short* __restrict__ B1,
                const float* __restrict__ bi0, const float* __restrict__ bi1,
                const float* __restrict__ g0,  const float* __restrict__ g1,
                const float* __restrict__ be0, const float* __restrict__ be1,
                unsigned short* __restrict__ o0, unsigned short* __restrict__ o1)
{
  __shared__ __align__(16) unsigned short As[128][64];
  __shared__ __align__(16) unsigned short Bs[128][64];

  const int tid = threadIdx.x;
  const int bm = blockIdx.x;
  const int z  = blockIdx.z;
  const unsigned short* Ag = z ? A1 : A0;
  const unsigned short* Bg = z ? B1 : B0;
  const float* bias = z ? bi1 : bi0;
  const float* gam  = z ? g1  : g0;
  const float* bet  = z ? be1 : be0;
  unsigned short* ob = z ? o1 : o0;
  const int row0 = bm * 128;

  const int lane = tid & 63;
  const int wv   = tid >> 6;
  const int wm   = (wv & 1) * 64;
  const int wn   = (wv >> 1) * 64;
  const int lr   = lane & 15;
  const int lq   = lane >> 4;
  const int r7   = lr & 7;

  const unsigned short* gA[4]; const unsigned short* gB[4];
  unsigned short* lA[4]; unsigned short* lB[4];
  #pragma unroll
  for (int i = 0; i < 4; i++) {
    const int c  = tid + i * 256;
    const int rr = c >> 3;
    const int gc = (c & 7) ^ (rr & 7);
    gA[i] = Ag + (long long)(row0 + rr) * 1024 + gc * 8;
    gB[i] = Bg + (long long)rr * 1024 + gc * 8;
    lA[i] = &As[0][0] + c * 8;
    lB[i] = &Bs[0][0] + c * 8;
  }

  floatx4 acc[4][4];
  const floatx4 zero = {0.f, 0.f, 0.f, 0.f};
  #pragma unroll
  for (int i = 0; i < 4; i++)
    #pragma unroll
    for (int j = 0; j < 4; j++) acc[i][j] = zero;

  for (int kt = 0; kt < 1024; kt += 64) {
    #pragma unroll
    for (int i = 0; i < 4; i++) {
      ASYNC_LD16(gA[i] + kt, lA[i]);
      ASYNC_LD16(gB[i] + kt, lB[i]);
    }
    __syncthreads();
    #pragma unroll
    for (int ks = 0; ks < 64; ks += 32) {
      const int k8 = ks >> 3;
      short8 af[4], bfv[4];
      #pragma unroll
      for (int i = 0; i < 4; i++) {
        const int sc = (lq + k8) ^ r7;
        af[i]  = *(const short8*)(&As[wm + i*16 + lr][sc * 8]);
        bfv[i] = *(const short8*)(&Bs[wn + i*16 + lr][sc * 8]);
      }
      #pragma unroll
      for (int mi = 0; mi < 4; mi++)
        #pragma unroll
        for (int ni = 0; ni < 4; ni++)
          acc[mi][ni] = MFMA_BF16(af[mi], bfv[ni], acc[mi][ni], 0, 0, 0);
    }
    __syncthreads();
  }

  #pragma unroll
  for (int mi = 0; mi < 4; mi++)
    #pragma unroll
    for (int ni = 0; ni < 4; ni++)
      #pragma unroll
      for (int r = 0; r < 4; r++) {
        const int gm = row0 + wm + mi * 16 + lq * 4 + r;
        const int gn = wn + ni * 16 + lr;
        float v = acc[mi][ni][r] + bias[gn];
        ob[(long long)gm * 128 + gn] = f2u(siluf_(v) * gam[gn] + bet[gn]);
      }
}

// ---------------------------------------------------------------- 256x256 counted-vmcnt GEMM (g0)
// R4: pre-MFMA barriers REMOVED (4 barriers/tile, phase-END only). Correctness:
// each wave gates its MFMA on its own lgkmcnt(0); phase-end barrier then proves
// all waves' reads of that slot-group are complete before the next phase stages
// into it. Boundary: counted vmcnt(8) (t+2's 8 loads stay in flight).
__global__ __launch_bounds__(512, 2)
void gemm256(const unsigned short* __restrict__ A, int lda,
             const unsigned short* __restrict__ Bm, int ldb,
             int K,
             const float* __restrict__ bias,
             float* __restrict__ f0,
             unsigned short* __restrict__ b0)
{
  __shared__ __align__(16) unsigned short Ls[65536]; // 128 KiB: [buf2][A 16384 | B 16384]

  const int tid = threadIdx.x;
  const int bm = blockIdx.x, bn = blockIdx.y;
  const int row0 = bm * 256;
  const int col0 = bn * 256;

  const int lane = tid & 63;
  const int wv   = tid >> 6;
  const int wr   = (wv >> 2) * 128;
  const int wc   = (wv & 3) * 64;
  const int lr   = lane & 15;
  const int lq   = lane >> 4;
  const int r7   = lr & 7;

  const int rr0 = tid >> 3;
  const int swz = ((tid & 7) ^ (rr0 & 7)) * 8;
  const unsigned short* gA0 = A  + (long long)(row0 + rr0) * lda + swz;
  const unsigned short* gB0 = Bm + (long long)(col0 + rr0) * ldb + swz;
  const long long sA64 = 64LL * lda, sB64 = 64LL * ldb;
  unsigned short* lA0 = &Ls[0]     + tid * 8;
  unsigned short* lB0 = &Ls[16384] + tid * 8;

  floatx4 acc[8][4];
  const floatx4 zero = {0.f, 0.f, 0.f, 0.f};
  #pragma unroll
  for (int i = 0; i < 8; i++)
    #pragma unroll
    for (int j = 0; j < 4; j++) acc[i][j] = zero;

  const int NT = K >> 6;

  #pragma unroll
  for (int i = 0; i < 4; i++) ASYNC_LD16(gA0 + i * sA64,      lA0 + i * 4096);
  #pragma unroll
  for (int i = 0; i < 4; i++) ASYNC_LD16(gB0 + i * sB64,      lB0 + i * 4096);
  #pragma unroll
  for (int i = 0; i < 4; i++) ASYNC_LD16(gA0 + i * sA64 + 64, lA0 + i * 4096 + 32768);
  #pragma unroll
  for (int i = 0; i < 4; i++) ASYNC_LD16(gB0 + i * sB64 + 64, lB0 + i * 4096 + 32768);
  asm volatile("s_waitcnt vmcnt(8)" ::: "memory");
  SBAR();

  for (int t = 0; t < NT; ++t) {
    const int cb = (t & 1) << 15;
    const unsigned short* Ab = &Ls[cb];
    const unsigned short* Bb = &Ls[cb + 16384];
    const bool st = (t + 2) < NT;
    const int kt2 = (t + 2) << 6;

    short8 afA[4][2], afB[4][2], bf01[2][2], bf23[2][2];

    // ---- phase 1: 12 ds_reads (afA mi0-3, bf01 ni0-1); MFMA Q(0-3, 0-1)
    #pragma unroll
    for (int mi = 0; mi < 4; mi++)
      #pragma unroll
      for (int k = 0; k < 2; k++)
        afA[mi][k] = *(const short8*)(Ab + (wr + mi*16 + lr) * 64 + (((k<<2) + lq) ^ r7) * 8);
    #pragma unroll
    for (int ni = 0; ni < 2; ni++)
      #pragma unroll
      for (int k = 0; k < 2; k++)
        bf01[ni][k] = *(const short8*)(Bb + (wc + ni*16 + lr) * 64 + (((k<<2) + lq) ^ r7) * 8);
    asm volatile("s_waitcnt lgkmcnt(0)" ::: "memory");
    __builtin_amdgcn_sched_barrier(0);
    __builtin_amdgcn_s_setprio(1);
    #pragma unroll
    for (int mi = 0; mi < 4; mi++)
      #pragma unroll
      for (int ni = 0; ni < 2; ni++)
        #pragma unroll
        for (int k = 0; k < 2; k++)
          acc[mi][ni] = MFMA_BF16(afA[mi][k], bf01[ni][k], acc[mi][ni], 0, 0, 0);
    __builtin_amdgcn_s_setprio(0);
    SBAR();

    // ---- phase 2: 4 ds_reads (bf23 ni2-3); MFMA Q(0-3, 2-3)
    #pragma unroll
    for (int ni = 0; ni < 2; ni++)
      #pragma unroll
      for (int k = 0; k < 2; k++)
        bf23[ni][k] = *(const short8*)(Bb + (wc + (ni+2)*16 + lr) * 64 + (((k<<2) + lq) ^ r7) * 8);
    asm volatile("s_waitcnt lgkmcnt(0)" ::: "memory");
    __builtin_amdgcn_sched_barrier(0);
    __builtin_amdgcn_s_setprio(1);
    #pragma unroll
    for (int mi = 0; mi < 4; mi++)
      #pragma unroll
      for (int ni = 0; ni < 2; ni++)
        #pragma unroll
        for (int k = 0; k < 2; k++)
          acc[mi][ni+2] = MFMA_BF16(afA[mi][k], bf23[ni][k], acc[mi][ni+2], 0, 0, 0);
    __builtin_amdgcn_s_setprio(0);
    SBAR();   // B slots of this buffer fully consumed (every wave lgkm-gated)

    // ---- phase 3: 8 ds_reads (afB mi4-7); stage B(t+2) into freed B slots
    #pragma unroll
    for (int mi = 0; mi < 4; mi++)
      #pragma unroll
      for (int k = 0; k < 2; k++)
        afB[mi][k] = *(const short8*)(Ab + (wr + (mi+4)*16 + lr) * 64 + (((k<<2) + lq) ^ r7) * 8);
    if (st) {
      #pragma unroll
      for (int i = 0; i < 4; i++) ASYNC_LD16(gB0 + i * sB64 + kt2, lB0 + i * 4096 + cb);
    }
    asm volatile("s_waitcnt lgkmcnt(0)" ::: "memory");
    __builtin_amdgcn_sched_barrier(0);
    __builtin_amdgcn_s_setprio(1);
    #pragma unroll
    for (int mi = 0; mi < 4; mi++)
      #pragma unroll
      for (int ni = 0; ni < 2; ni++)
        #pragma unroll
        for (int k = 0; k < 2; k++)
          acc[mi+4][ni] = MFMA_BF16(afB[mi][k], bf01[ni][k], acc[mi+4][ni], 0, 0, 0);
    __builtin_amdgcn_s_setprio(0);
    SBAR();   // A slots of this buffer fully consumed

    // ---- phase 4: stage A(t+2) into freed A slots; MFMA Q(4-7, 2-3); boundary
    if (st) {
      #pragma unroll
      for (int i = 0; i < 4; i++) ASYNC_LD16(gA0 + i * sA64 + kt2, lA0 + i * 4096 + cb);
    }
    __builtin_amdgcn_s_setprio(1);
    #pragma unroll
    for (int mi = 0; mi < 4; mi++)
      #pragma unroll
      for (int ni = 0; ni < 2; ni++)
        #pragma unroll
        for (int k = 0; k < 2; k++)
          acc[mi+4][ni+2] = MFMA_BF16(afB[mi][k], bf23[ni][k], acc[mi+4][ni+2], 0, 0, 0);
    __builtin_amdgcn_s_setprio(0);
    if (st) { asm volatile("s_waitcnt vmcnt(8)" ::: "memory"); }
    else    { asm volatile("s_waitcnt vmcnt(0)" ::: "memory"); }
    SBAR();
  }

  // epilogue (EPI0, N=2048: u for gn<1024 else r)
  #pragma unroll
  for (int mi = 0; mi < 8; mi++)
    #pragma unroll
    for (int ni = 0; ni < 4; ni++)
      #pragma unroll
      for (int r = 0; r < 4; r++) {
        const int gm = row0 + wr + mi * 16 + lq * 4 + r;
        const int gn = col0 + wc + ni * 16 + lr;
        float v = acc[mi][ni][r] + bias[gn];
        if (gn < 1024) {
          ((unsigned short*)f0)[(long long)gm * 1024 + gn] = f2u(sigmoidf_(v)); // u bf16
        } else {
          b0[(long long)gm * 1024 + (gn - 1024)] = f2u(siluf_(v));    // r
        }
      }
}

// ---------------------------------------------------------------- 256x128 counted-vmcnt GEMM
// R4 new: BM=256, BN=128, BK=64, 8 waves 4Mx2N (wave 64x64, acc[4][4]).
// LDS 96 KiB = 2 x (A 32KB + B 16KB). TWO phases, TWO barriers per tile:
//   ph1: all 16 ds_reads (afA 8, bfv 8); lgkmcnt(0); 16 MFMA (ni0-1); SBAR
//        -> after this barrier every wave's LDS reads of tile t are complete.
//   ph2: stage 6 loads of t+2 into the SAME buffer (t+2 = t mod 2, slots just
//        freed); 16 MFMA (ni2-3, operands already in registers); boundary
//        vmcnt(6) (t+1 landed, t+2's 6 stay in flight); SBAR.
// Grids land exactly 256 blocks for g2 (4,64), g4 (8,8,4), g5 (32,8).
// EPI: 2 = v proj swapped (gm=e, gn=(b,s)); 4 = PV h=acc/rowsum * r;
//      5 = final out = q + u*(tanh(.)-q)
template<int EPI>
__global__ __launch_bounds__(512, 2)
void gemm_n128(const unsigned short* __restrict__ A, long long bsA, int lda,
               const unsigned short* __restrict__ Bm, long long bsB, int ldb,
               int K,
               const float* __restrict__ bias,
               float* __restrict__ f0,
               unsigned short* __restrict__ b0,
               const unsigned short* __restrict__ rmul,
               const float* __restrict__ qin)
{
  __shared__ __align__(16) unsigned short Ls[49152]; // 96 KiB: {A0,B0,A1,B1}

  const int tid = threadIdx.x;
  const int bm = blockIdx.x, bn = blockIdx.y, bz = blockIdx.z;
  const unsigned short* Ag = A  + (long long)bz * bsA;
  const unsigned short* Bg = Bm + (long long)bz * bsB;
  const int row0 = bm * 256;
  const int col0 = bn * 128;

  const int lane = tid & 63;
  const int wv   = tid >> 6;
  const int wr   = (wv & 3) * 64;    // wave row: 0/64/128/192
  const int wc   = (wv >> 2) * 64;   // wave col: 0/64
  const int lr   = lane & 15;
  const int lq   = lane >> 4;
  const int r7   = lr & 7;

  const int rr0 = tid >> 3;
  const int swz = ((tid & 7) ^ (rr0 & 7)) * 8;
  const unsigned short* gA0 = Ag + (long long)(row0 + rr0) * lda + swz;  // + i*sA64, i<4
  const unsigned short* gB0 = Bg + (long long)(col0 + rr0) * ldb + swz;  // + i*sB64, i<2
  const long long sA64 = 64LL * lda, sB64 = 64LL * ldb;
  unsigned short* lA0 = &Ls[0]     + tid * 8;   // + i*4096 + cb
  unsigned short* lB0 = &Ls[16384] + tid * 8;

  floatx4 acc[4][4];
  const floatx4 zero = {0.f, 0.f, 0.f, 0.f};
  #pragma unroll
  for (int i = 0; i < 4; i++)
    #pragma unroll
    for (int j = 0; j < 4; j++) acc[i][j] = zero;

  const int NT = K >> 6;

  // prologue: tile0 -> buf0, tile1 -> buf1; wait tile0 (t1's 6 stay in flight)
  #pragma unroll
  for (int i = 0; i < 4; i++) ASYNC_LD16(gA0 + i * sA64,      lA0 + i * 4096);
  #pragma unroll
  for (int i = 0; i < 2; i++) ASYNC_LD16(gB0 + i * sB64,      lB0 + i * 4096);
  #pragma unroll
  for (int i = 0; i < 4; i++) ASYNC_LD16(gA0 + i * sA64 + 64, lA0 + i * 4096 + 24576);
  #pragma unroll
  for (int i = 0; i < 2; i++) ASYNC_LD16(gB0 + i * sB64 + 64, lB0 + i * 4096 + 24576);
  asm volatile("s_waitcnt vmcnt(6)" ::: "memory");
  SBAR();

  for (int t = 0; t < NT; ++t) {
    const int cb = (t & 1) * 24576;
    const unsigned short* Ab = &Ls[cb];
    const unsigned short* Bb = &Ls[cb + 16384];
    const bool st = (t + 2) < NT;
    const int kt2 = (t + 2) << 6;

    short8 afA[4][2], bfv[4][2];

    // ---- phase 1: all 16 ds_reads; MFMA (mi x ni0-1)
    #pragma unroll
    for (int mi = 0; mi < 4; mi++)
      #pragma unroll
      for (int k = 0; k < 2; k++)
        afA[mi][k] = *(const short8*)(Ab + (wr + mi*16 + lr) * 64 + (((k<<2) + lq) ^ r7) * 8);
    #pragma unroll
    for (int ni = 0; ni < 4; ni++)
      #pragma unroll
      for (int k = 0; k < 2; k++)
        bfv[ni][k] = *(const short8*)(Bb + (wc + ni*16 + lr) * 64 + (((k<<2) + lq) ^ r7) * 8);
    asm volatile("s_waitcnt lgkmcnt(0)" ::: "memory");
    __builtin_amdgcn_sched_barrier(0);
    __builtin_amdgcn_s_setprio(1);
    #pragma unroll
    for (int mi = 0; mi < 4; mi++)
      #pragma unroll
      for (int ni = 0; ni < 2; ni++)
        #pragma unroll
        for (int k = 0; k < 2; k++)
          acc[mi][ni] = MFMA_BF16(afA[mi][k], bfv[ni][k], acc[mi][ni], 0, 0, 0);
    __builtin_amdgcn_s_setprio(0);
    SBAR();   // all waves' reads of tile t complete -> buffer slots free

    // ---- phase 2: stage t+2 (6 loads, same-parity buffer); MFMA (mi x ni2-3)
    if (st) {
      #pragma unroll
      for (int i = 0; i < 4; i++) ASYNC_LD16(gA0 + i * sA64 + kt2, lA0 + i * 4096 + cb);
      #pragma unroll
      for (int i = 0; i < 2; i++) ASYNC_LD16(gB0 + i * sB64 + kt2, lB0 + i * 4096 + cb);
    }
    __builtin_amdgcn_s_setprio(1);
    #pragma unroll
    for (int mi = 0; mi < 4; mi++)
      #pragma unroll
      for (int ni = 0; ni < 2; ni++)
        #pragma unroll
        for (int k = 0; k < 2; k++)
          acc[mi][ni+2] = MFMA_BF16(afA[mi][k], bfv[ni+2][k], acc[mi][ni+2], 0, 0, 0);
    __builtin_amdgcn_s_setprio(0);
    if (st) { asm volatile("s_waitcnt vmcnt(6)" ::: "memory"); }
    else    { asm volatile("s_waitcnt vmcnt(0)" ::: "memory"); }
    SBAR();
  }

  // ---------------------------------------------------------------- epilogue
  #pragma unroll
  for (int mi = 0; mi < 4; mi++) {
    float iv[4];
    if constexpr (EPI == 4) {
      #pragma unroll
      for (int r = 0; r < 4; r++) {
        const int gm = row0 + wr + mi * 16 + lq * 4 + r;
        iv[r] = 1.0f / f0[(long long)bz * 2048 + gm];
      }
    }
    #pragma unroll
    for (int ni = 0; ni < 4; ni++) {
      #pragma unroll
      for (int r = 0; r < 4; r++) {
        const int gm = row0 + wr + mi * 16 + lq * 4 + r;
        const int gn = col0 + wc + ni * 16 + lr;
        float v = acc[mi][ni][r];
        if constexpr (EPI == 2) {
          v += bias[gm];                                               // bias by e-row
          const int b = gn >> 11, s = gn & 2047;
          b0[((long long)b * 1024 + gm) * 2048 + s] = f2u(siluf_(v));  // v^T coalesced
        } else if constexpr (EPI == 4) {
          const long long idx = ((long long)gm * 4 + bz) * 1024 + gn;  // (t,b,e)
          b0[idx] = f2u(v * iv[r] * u2f(rmul[idx]));                   // h*r
        } else { // EPI == 5
          const long long idx = (long long)gm * 1024 + gn;
          const float tv = tanhf(v + bias[gn]);
          const float qv = qin[idx];
          f0[idx] = qv + u2f(rmul[idx]) * (tv - qv);                   // final out
        }
      }
    }
  }
}

// ---------------------------------------------------------------- launch
extern "C" void kernel_launch(void* const* d_in, const int* in_sizes, int n_in,
                              void* d_out, int out_size, void* d_ws, size_t ws_size,
                              hipStream_t stream)
{
  (void)in_sizes; (void)n_in; (void)out_size; (void)ws_size;
  const float* query = (const float*)d_in[0];
  const float* key   = (const float*)d_in[1];
  const float* Wq    = (const float*)d_in[2];
  const float* bq    = (const float*)d_in[3];
  const float* Wk    = (const float*)d_in[4];
  const float* bk    = (const float*)d_in[5];
  const float* Wv    = (const float*)d_in[6];
  const float* bv    = (const float*)d_in[7];
  const float* Wh    = (const float*)d_in[8];
  const float* bh    = (const float*)d_in[9];
  const float* gamma = (const float*)d_in[10];
  const float* beta  = (const float*)d_in[11];
  float* out = (float*)d_out;

  char* p = (char*)d_ws;
  auto take = [&](size_t bytes) -> char* {
    char* r = p; p += (bytes + 255) & ~(size_t)255; return r;
  };
  unsigned short* qbf = (unsigned short*)take(8192ULL * 1024 * 2); // query bf16 (T*B,E)
  unsigned short* kbr = (unsigned short*)take(8192ULL * 1024 * 2); // key bf16 [B][S][E]
  unsigned short* Wqb = (unsigned short*)take(2176ULL * 1024 * 2);
  unsigned short* Wkb = (unsigned short*)take(128ULL  * 1024 * 2);
  unsigned short* Wvb = (unsigned short*)take(1024ULL * 1024 * 2);
  unsigned short* Whb = (unsigned short*)take(1024ULL * 1024 * 2);
  unsigned short* ub  = (unsigned short*)take(8192ULL * 1024 * 2); // u gate bf16
  unsigned short* rbf = (unsigned short*)take(8192ULL * 1024 * 2); // r bf16
  unsigned short* qpj = (unsigned short*)take(8192ULL * 128 * 2);  // q (T,B,Z)
  unsigned short* kpj = (unsigned short*)take(8192ULL * 128 * 2);  // k [B][S][Z]
  unsigned short* vT  = (unsigned short*)take(4ULL * 1024 * 2048 * 2); // v^T [B][E][S]
  unsigned short* Pb  = (unsigned short*)take(4ULL * 2048 * 2048 * 2); // P~ [B][T][S]
  unsigned short* hrb = (unsigned short*)take(8192ULL * 1024 * 2); // h*r bf16
  float*          rs  = (float*)take(4ULL * 2048 * 4);             // rowsums [B][T]

  dim3 blk(256);
  dim3 gblk(512);
  cast_act<<<16384, blk, 0, stream>>>(query, key, qbf, kbr);
  cast_w<<<4352, blk, 0, stream>>>(Wq, Wk, Wv, Wh, Wqb, Wkb, Wvb, Whb);
  hipMemsetAsync(rs, 0, 4ULL * 2048 * 4, stream);

  // merged N=128 projections: z=0 q-slice (Wq rows 2048..2175), z=1 k-proj
  gemm_nz128<<<dim3(64, 1, 2), blk, 0, stream>>>(
      qbf, kbr, Wqb + 2048LL * 1024, Wkb,
      bq + 2048, bk, gamma, gamma + 128, beta, beta + 128, qpj, kpj);
  // g0: Wq main (cols 0..2047): u (sigmoid) + r (silu)
  gemm256<<<dim3(32, 8, 1), gblk, 0, stream>>>(qbf, 1024, Wqb, 1024, 1024,
      bq, (float*)ub, rbf);
  // g2: v^T[b][e][s] = silu(Wv @ kbr^T + bv)  (swapped: 256 blocks)
  gemm_n128<2><<<dim3(4, 64, 1), gblk, 0, stream>>>(Wvb, 0, 1024, kbr, 0, 1024, 1024,
      bv, nullptr, vT, nullptr, nullptr);
  // g3: P~[b][t][s] = exp(scaling * q_b @ k_b^T), rowsums -> rs (atomic)
  gemm_bt<3><<<dim3(16, 16, 4), blk, 0, stream>>>(qpj, 128, 512, kpj, 2048LL * 128, 128, 128,
      rs, Pb);
  // g4: hr[t,b,e] = (P~_b @ vT_b^T)/rowsum * r
  gemm_n128<4><<<dim3(8, 8, 4), gblk, 0, stream>>>(Pb, 2048LL * 2048, 2048,
      vT, 1024LL * 2048, 2048, 2048,
      nullptr, rs, hrb, rbf, nullptr);
  // g5: out = query + u * (tanh(hr @ Wh^T + bh) - query)
  gemm_n128<5><<<dim3(32, 8, 1), gblk, 0, stream>>>(hrb, 0, 1024, Whb, 0, 1024, 1024,
      bh, out, nullptr, ub, query);
}